// Round 6
// baseline (718.520 us; speedup 1.0000x reference)
//
#include <hip/hip_runtime.h>
#include <hip/hip_fp16.h>

typedef _Float16 half8 __attribute__((ext_vector_type(8)));
typedef float f32x4 __attribute__((ext_vector_type(4)));
typedef unsigned long long u64;
typedef unsigned u32;

#define IN_DIM 784
#define KPAD   832            // 13 * 64
#define NKT    13
#define HIDDEN 8192
#define BATCH  16384
#define OUTD   10
#define N1 (HIDDEN * IN_DIM)  // 6422528
#define J1 (N1 / 2)
#define N2 (OUTD * HIDDEN)    // 81920
#define J2 (N2 / 2)

// ---- workspace layout (bytes) ----
#define WS_META 0         // u32[4]: T1,cut1,T2,cut2
#define WS_SEL1 64        // u32[2]: {jrem, prefix}
#define WS_SEL2 96
#define WS_CNT  128       // u32[2]: candidate counts
#define CTL_WORDS 1024    // zero first 4KB of ws
#define WS_LOG  163840    // [16384][10] f32 atomic accumulator
#define WS_XH   (WS_LOG + BATCH * OUTD * 4)            // [16384][832] f16
#define WS_W1H  (WS_XH + (size_t)BATCH * KPAD * 2)     // [8192][832] f16
#define WS_W2H  (WS_W1H + (size_t)HIDDEN * KPAD * 2)   // [16][8192] f16
#define WS_NEED (WS_W2H + 16 * HIDDEN * 2)             // ~41.9 MB

// selection scratch ALIASED inside W1H (dead before cvt_w12 writes W1H)
#define WS_SL01 WS_W1H                     // 256 x 2048 u32 (s1 pass0 slices)
#define WS_SL02 (WS_W1H + 2097152)         // 16 x 2048 u32
#define WS_SL11 (WS_SL02 + 131072)         // 256 x 1024 u32 (s1 pass1 slices)
#define WS_SL12 (WS_SL11 + 1048576)        // 16 x 1024 u32
#define WS_CAND1 (WS_W1H + 4194304)        // 8192 u64
#define WS_CAND2 (WS_CAND1 + 65536)        // 8192 u64

#define CVT_X_BLKS 6656
#define ZERO_BLKS  668
#define H1BLK 256
#define H2BLK 16
#define ZERO_TOT (CTL_WORDS + BATCH * OUTD)

// ---------------- K1: cvt_x + zero ctl/logits + hist pass0 (slices, no atomics) ----------------
__global__ void k1_prep(const float* __restrict__ x, _Float16* __restrict__ xh,
                        const float* __restrict__ s1, const float* __restrict__ s2,
                        u32* __restrict__ ws) {
  __shared__ u32 lh[2048];
  int bx = blockIdx.x;
  if (bx < CVT_X_BLKS) {
    int c = bx * 256 + threadIdx.x;       // 16384*104 chunks of 8
    int row = c / 104, cc = c % 104;
    half8 v;
#pragma unroll
    for (int j = 0; j < 8; ++j) {
      int col = cc * 8 + j;
      float f = (col < IN_DIM) ? x[(size_t)row * IN_DIM + col] : 0.f;
      v[j] = (_Float16)f;
    }
    *(half8*)(xh + (size_t)row * KPAD + cc * 8) = v;
    return;
  }
  bx -= CVT_X_BLKS;
  if (bx < ZERO_BLKS) {
    for (int i = bx * 256 + threadIdx.x; i < ZERO_TOT; i += ZERO_BLKS * 256) {
      if (i < CTL_WORDS) {
        u32 v = 0u;
        if (i == WS_SEL1 / 4) v = J1;
        else if (i == WS_SEL2 / 4) v = J2;
        ws[i] = v;
      } else {
        ws[WS_LOG / 4 + (i - CTL_WORDS)] = 0u;
      }
    }
    return;
  }
  bx -= ZERO_BLKS;
  // hist pass0: bins on key>>20 (11b); per-block slice, plain stores
  for (int i = threadIdx.x; i < 2048; i += 256) lh[i] = 0u;
  __syncthreads();
  const float* s; int n, nb, sb; u32* slice;
  if (bx < H1BLK) { s = s1; n = N1; nb = H1BLK; sb = bx;
    slice = ws + WS_SL01 / 4 + (size_t)sb * 2048; }
  else { s = s2; n = N2; nb = H2BLK; sb = bx - H1BLK;
    slice = ws + WS_SL02 / 4 + (size_t)sb * 2048; }
  for (int i = sb * 256 + threadIdx.x; i < n; i += nb * 256) {
    u32 k = __float_as_uint(s[i]) & 0x7FFFFFFFu;
    atomicAdd(&lh[k >> 20], 1u);
  }
  __syncthreads();
  for (int i = threadIdx.x; i < 2048; i += 256) slice[i] = lh[i];
}

// ---------------- hist pass1 (prefix-filtered, slices) ----------------
__global__ void sel_hist1(const float* __restrict__ s1, const float* __restrict__ s2,
                          u32* __restrict__ ws) {
  __shared__ u32 lh[1024];
  for (int i = threadIdx.x; i < 1024; i += 256) lh[i] = 0u;
  __syncthreads();
  int bx = blockIdx.x;
  const float* s; int n, nb, sb; u32* slice; const u32* sel;
  if (bx < H1BLK) { s = s1; n = N1; nb = H1BLK; sb = bx;
    slice = ws + WS_SL11 / 4 + (size_t)sb * 1024; sel = ws + WS_SEL1 / 4; }
  else { s = s2; n = N2; nb = H2BLK; sb = bx - H1BLK;
    slice = ws + WS_SL12 / 4 + (size_t)sb * 1024; sel = ws + WS_SEL2 / 4; }
  u32 prefix = sel[1];
  for (int i = sb * 256 + threadIdx.x; i < n; i += nb * 256) {
    u32 k = __float_as_uint(s[i]) & 0x7FFFFFFFu;
    if ((k >> 20) == prefix) atomicAdd(&lh[(k >> 10) & 0x3FFu], 1u);
  }
  __syncthreads();
  for (int i = threadIdx.x; i < 1024; i += 256) slice[i] = lh[i];
}

// ---------------- scan: reduce slices + Hillis-Steele + owner tail ----------------
template <int PASS>
__global__ void sel_scan_t(u32* __restrict__ ws) {
  __shared__ u32 part[256], incl[256], histr[2048];
  constexpr int nbins = PASS == 0 ? 2048 : 1024;
  constexpr int bits  = PASS == 0 ? 11 : 10;
  constexpr int per   = nbins / 256;
  const u32* slice; int nsl;
  if (blockIdx.x == 0) { slice = ws + (PASS == 0 ? WS_SL01 : WS_SL11) / 4; nsl = H1BLK; }
  else                 { slice = ws + (PASS == 0 ? WS_SL02 : WS_SL12) / 4; nsl = H2BLK; }
  u32* sel = ws + ((blockIdx.x == 0) ? WS_SEL1 : WS_SEL2) / 4;
  u32 sums[per];
#pragma unroll
  for (int i = 0; i < per; ++i) sums[i] = 0u;
  for (int sl = 0; sl < nsl; ++sl) {
    const u32* sp = slice + (size_t)sl * nbins + threadIdx.x * per;
#pragma unroll
    for (int i = 0; i < per; ++i) sums[i] += sp[i];
  }
  u32 ssum = 0;
#pragma unroll
  for (int i = 0; i < per; ++i) { histr[threadIdx.x * per + i] = sums[i]; ssum += sums[i]; }
  part[threadIdx.x] = ssum;
  incl[threadIdx.x] = ssum;
  __syncthreads();
  for (int off = 1; off < 256; off <<= 1) {
    u32 v = (threadIdx.x >= off) ? incl[threadIdx.x - off] : 0u;
    __syncthreads();
    incl[threadIdx.x] += v;
    __syncthreads();
  }
  u32 jrem = sel[0];
  u32 excl = incl[threadIdx.x] - part[threadIdx.x];
  if (jrem >= excl && jrem < excl + part[threadIdx.x]) {   // unique owner thread
    u32 cum = excl; int b = threadIdx.x * per;
    for (;; ++b) { u32 h = histr[b]; if (cum + h > jrem) break; cum += h; }
    sel[0] = jrem - cum;
    sel[1] = (sel[1] << bits) | (u32)b;
  }
}

// ---------------- collect candidates matching 21-bit prefix ----------------
__global__ void sel_collect(const float* __restrict__ s1, const float* __restrict__ s2,
                            u32* __restrict__ ws) {
  int bx = blockIdx.x;
  const float* s; int n, nb, sb; u64* cand; u32* cnt; const u32* sel;
  if (bx < H1BLK) { s = s1; n = N1; nb = H1BLK; sb = bx;
    cand = (u64*)(ws + WS_CAND1 / 4); cnt = ws + WS_CNT / 4; sel = ws + WS_SEL1 / 4; }
  else { s = s2; n = N2; nb = H2BLK; sb = bx - H1BLK;
    cand = (u64*)(ws + WS_CAND2 / 4); cnt = ws + WS_CNT / 4 + 1; sel = ws + WS_SEL2 / 4; }
  u32 prefix21 = sel[1];
  for (int i = sb * 256 + threadIdx.x; i < n; i += nb * 256) {
    u32 k = __float_as_uint(s[i]) & 0x7FFFFFFFu;
    if ((k >> 10) == prefix21) {
      u32 p = atomicAdd(cnt, 1u);
      if (p < 8192u) cand[p] = ((u64)k << 32) | (u32)i;
    }
  }
}

// exact rank-m candidate by (key, idx) -> stable argsort tie semantics (LDS-staged)
__global__ void sel_final(u32* __restrict__ ws) {
  __shared__ u64 lc[4096];
  int t = blockIdx.x;
  const u64* cand = (const u64*)(ws + (t == 0 ? WS_CAND1 : WS_CAND2) / 4);
  u32 n = ws[WS_CNT / 4 + t]; if (n > 8192u) n = 8192u;
  u32 nl = n < 4096u ? n : 4096u;
  for (u32 i = threadIdx.x; i < nl; i += 256) lc[i] = cand[i];
  __syncthreads();
  u32 m = ws[(t == 0 ? WS_SEL1 : WS_SEL2) / 4];   // jrem after both scans
  for (u32 ci = threadIdx.x; ci < n; ci += 256) {
    u64 me = (ci < nl) ? lc[ci] : cand[ci];
    u32 r = 0;
    for (u32 j = 0; j < nl; ++j) r += (lc[j] < me) ? 1u : 0u;
    for (u32 j = nl; j < n; ++j) r += (cand[j] < me) ? 1u : 0u;
    if (r == m) {
      ws[WS_META / 4 + t * 2]     = (u32)(me >> 32);   // T
      ws[WS_META / 4 + t * 2 + 1] = (u32)me;           // cut (flat idx)
    }
  }
}

// ---------------- masked weight converts (f32 -> padded f16) ----------------
__global__ void cvt_w12(const float* __restrict__ w1, const float* __restrict__ s1,
                        const float* __restrict__ w2, const float* __restrict__ s2,
                        const u32* __restrict__ meta,
                        _Float16* __restrict__ w1h, _Float16* __restrict__ w2h) {
  if (blockIdx.x < 3328) {
    int c = blockIdx.x * 256 + threadIdx.x;     // 8192*104
    int row = c / 104, cc = c % 104;
    u32 T = meta[0], cut = meta[1];
    half8 v;
#pragma unroll
    for (int j = 0; j < 8; ++j) {
      int col = cc * 8 + j;
      float f = 0.f;
      if (col < IN_DIM) {
        u32 flat = (u32)(row * IN_DIM + col);
        u32 k = __float_as_uint(s1[flat]) & 0x7FFFFFFFu;
        bool keep = (k > T) || (k == T && flat >= cut);
        f = keep ? w1[flat] : 0.f;
      }
      v[j] = (_Float16)f;
    }
    *(half8*)(w1h + (size_t)row * KPAD + cc * 8) = v;
  } else {
    int c = (blockIdx.x - 3328) * 256 + threadIdx.x;   // 16*1024
    int o = c >> 10, cc = c & 1023;
    u32 T = meta[2], cut = meta[3];
    half8 v;
#pragma unroll
    for (int j = 0; j < 8; ++j) {
      float f = 0.f;
      if (o < OUTD) {
        u32 flat = (u32)(o * HIDDEN + cc * 8 + j);
        u32 k = __float_as_uint(s2[flat]) & 0x7FFFFFFFu;
        bool keep = (k > T) || (k == T && flat >= cut);
        f = keep ? w2[flat] : 0.f;
      }
      v[j] = (_Float16)f;
    }
    *(half8*)(w2h + (size_t)o * HIDDEN + cc * 8) = v;
  }
}

// ---------------- fused GEMM1 + relu + GEMM2 epilogue ----------------
// 256x256 tile, BK=64, 8-phase-per-2-Ktiles schedule (4 phases/K-tile, 16 MFMA each).
// LDS: 2 buffers x {A0,A1,B0,B1} half-tiles of 16KB. Stage next tile's halves in
// phases 0-1; single vmcnt(0) at tile end (all waited loads >=2 phases old).
__device__ __forceinline__ void gload16(const _Float16* g, _Float16* l) {
  __builtin_amdgcn_global_load_lds((const __attribute__((address_space(1))) void*)g,
                                   (__attribute__((address_space(3))) void*)l, 16, 0, 0);
}

__global__ __launch_bounds__(512, 2) void gemm_fused(
    const _Float16* __restrict__ xh, const _Float16* __restrict__ w1h,
    const _Float16* __restrict__ w2h, float* __restrict__ logits) {
  extern __shared__ __align__(16) char smem[];   // 131072

  const int tid  = threadIdx.x;
  const int lane = tid & 63;
  const int wid  = tid >> 6;          // 8 waves: 2M x 4N
  const int wm   = wid >> 2, wn = wid & 3;

  // XCD-bijective swizzle (2048 % 8 == 0) + pm-group-of-8 for L2
  int v   = (blockIdx.x & 7) * 256 + (blockIdx.x >> 3);
  int g   = v >> 8, r = v & 255;
  int pm  = g * 8 + (r & 7);          // 0..63
  int pn  = r >> 3;                   // 0..31

  const _Float16* Ab = xh  + (size_t)pm * 256 * KPAD;
  const _Float16* Bb = w1h + (size_t)pn * 256 * KPAD;

  f32x4 acc[8][4] = {};

  // stage one 16KB half-tile (128 rows x 64 cols f16): h 0/1 = A halves, 2/3 = B halves
  auto stage_half = [&](int kt, int b, int h) {
    const _Float16* src = (h < 2 ? Ab : Bb) + (size_t)((h & 1) * 128) * KPAD;
    _Float16* dst = (_Float16*)(smem + b * 65536 + h * 16384);
#pragma unroll
    for (int i = 0; i < 2; ++i) {
      int slot = i * 512 + tid;                 // 0..1023
      int row  = slot >> 3, ch = slot & 7;
      int cl   = ch ^ (row & 7);                // pre-swizzled source, linear LDS dest
      gload16(src + (size_t)row * KPAD + kt * 64 + cl * 8, dst + slot * 8);
    }
  };

  // prologue: tile 0 into buffer 0
  stage_half(0, 0, 0); stage_half(0, 0, 1); stage_half(0, 0, 2); stage_half(0, 0, 3);
  asm volatile("s_waitcnt vmcnt(0)" ::: "memory");
  __builtin_amdgcn_s_barrier();

  for (int t = 0; t < NKT; ++t) {
    const int b = t & 1;
    const _Float16* A_ = (const _Float16*)(smem + b * 65536 + wm * 16384);
    const _Float16* B_ = (const _Float16*)(smem + b * 65536 + 32768 + (wn >> 1) * 16384);
    half8 bf[4];
#pragma unroll
    for (int ks = 0; ks < 2; ++ks) {
#pragma unroll
      for (int mih = 0; mih < 2; ++mih) {
        // ---- phase: ds-reads for this quadrant ----
        half8 af[4];
#pragma unroll
        for (int q = 0; q < 4; ++q) {
          int lrow = (mih * 4 + q) * 16 + (lane & 15);
          int ch   = (ks * 4 + (lane >> 4)) ^ (lrow & 7);
          af[q] = *(const half8*)(A_ + lrow * 64 + ch * 8);
        }
        if (mih == 0) {
#pragma unroll
          for (int ni = 0; ni < 4; ++ni) {
            int lrow = (wn & 1) * 64 + ni * 16 + (lane & 15);
            int ch   = (ks * 4 + (lane >> 4)) ^ (lrow & 7);
            bf[ni] = *(const half8*)(B_ + lrow * 64 + ch * 8);
          }
        }
        // ---- stage next tile's halves during phases 0,1 (2 halves each) ----
        if (ks == 0 && t + 1 < NKT) {
          stage_half(t + 1, b ^ 1, mih * 2 + 0);
          stage_half(t + 1, b ^ 1, mih * 2 + 1);
        }
        __builtin_amdgcn_s_barrier();
        asm volatile("s_waitcnt lgkmcnt(0)" ::: "memory");
        __builtin_amdgcn_sched_barrier(0);
        __builtin_amdgcn_s_setprio(1);
#pragma unroll
        for (int q = 0; q < 4; ++q)
#pragma unroll
          for (int ni = 0; ni < 4; ++ni)
            acc[mih * 4 + q][ni] =
                __builtin_amdgcn_mfma_f32_16x16x32_f16(af[q], bf[ni], acc[mih * 4 + q][ni], 0, 0, 0);
        __builtin_amdgcn_s_setprio(0);
        if (ks == 1 && mih == 1) {
          // tile boundary: next tile's halves were issued >=2 phases ago
          asm volatile("s_waitcnt vmcnt(0)" ::: "memory");
        }
        __builtin_amdgcn_s_barrier();
      }
    }
  }

  // ---- epilogue: logits += relu(h) @ w2m^T over this block's 256 n-cols ----
  __syncthreads();
  _Float16* hb = (_Float16*)smem + wid * (64 * 72);   // per-wave [64][72] f16
  float* plog  = (float*)(smem + 73728);              // [256][16] f32

  for (int i = tid; i < 256 * 16; i += 512) plog[i] = 0.f;

  // round 0: rows mi 0..3
#pragma unroll
  for (int mi = 0; mi < 4; ++mi) {
    int r0 = mi * 16 + (lane >> 4) * 4;
#pragma unroll
    for (int ni = 0; ni < 4; ++ni) {
      int cl = ni * 16 + (lane & 15);
#pragma unroll
      for (int j = 0; j < 4; ++j) {
        float q = acc[mi][ni][j];
        hb[(r0 + j) * 72 + cl] = (_Float16)(q > 0.f ? q : 0.f);
      }
    }
  }
  __syncthreads();                               // plog zero visible (hb wave-private)

  half8 wb[2];
  int o = lane & 15;
#pragma unroll
  for (int ks = 0; ks < 2; ++ks)
    wb[ks] = *(const half8*)(w2h + (size_t)o * HIDDEN + pn * 256 + wn * 64 + ks * 32 + (lane >> 4) * 8);

  f32x4 lacc[8] = {};
#pragma unroll
  for (int mi = 0; mi < 4; ++mi)
#pragma unroll
    for (int ks = 0; ks < 2; ++ks) {
      int row = mi * 16 + (lane & 15);
      half8 a = *(const half8*)(hb + row * 72 + ks * 32 + (lane >> 4) * 8);
      lacc[mi] = __builtin_amdgcn_mfma_f32_16x16x32_f16(a, wb[ks], lacc[mi], 0, 0, 0);
    }

  // round 1: rows mi 4..7 (wave-private WAR on hb)
#pragma unroll
  for (int mi = 4; mi < 8; ++mi) {
    int r0 = (mi - 4) * 16 + (lane >> 4) * 4;
#pragma unroll
    for (int ni = 0; ni < 4; ++ni) {
      int cl = ni * 16 + (lane & 15);
#pragma unroll
      for (int j = 0; j < 4; ++j) {
        float q = acc[mi][ni][j];
        hb[(r0 + j) * 72 + cl] = (_Float16)(q > 0.f ? q : 0.f);
      }
    }
  }
#pragma unroll
  for (int mi = 4; mi < 8; ++mi)
#pragma unroll
    for (int ks = 0; ks < 2; ++ks) {
      int row = (mi - 4) * 16 + (lane & 15);
      half8 a = *(const half8*)(hb + row * 72 + ks * 32 + (lane >> 4) * 8);
      lacc[mi] = __builtin_amdgcn_mfma_f32_16x16x32_f16(a, wb[ks], lacc[mi], 0, 0, 0);
    }

  if (o < OUTD) {
#pragma unroll
    for (int mi = 0; mi < 8; ++mi)
#pragma unroll
      for (int j = 0; j < 4; ++j) {
        int row = wm * 128 + mi * 16 + (lane >> 4) * 4 + j;
        atomicAdd(&plog[row * 16 + o], lacc[mi][j]);
      }
  }
  __syncthreads();
  for (int i = tid; i < 256 * OUTD; i += 512) {
    int row = i / OUTD, oo = i % OUTD;
    atomicAdd(&logits[((size_t)pm * 256 + row) * OUTD + oo], plog[row * 16 + oo]);
  }
}

// ---------------- log_softmax ----------------
__global__ void final_ls(const float* __restrict__ logits, float* __restrict__ out) {
  int row = blockIdx.x * 256 + threadIdx.x;     // 16384
  float l[OUTD];
#pragma unroll
  for (int oo = 0; oo < OUTD; ++oo) l[oo] = logits[(size_t)row * OUTD + oo];
  float mx = l[0];
#pragma unroll
  for (int oo = 1; oo < OUTD; ++oo) mx = fmaxf(mx, l[oo]);
  float s = 0.f;
#pragma unroll
  for (int oo = 0; oo < OUTD; ++oo) s += expf(l[oo] - mx);
  float lse = mx + logf(s);
#pragma unroll
  for (int oo = 0; oo < OUTD; ++oo) out[(size_t)row * OUTD + oo] = l[oo] - lse;
}

// ---------------- launch ----------------
extern "C" void kernel_launch(void* const* d_in, const int* in_sizes, int n_in,
                              void* d_out, int out_size, void* d_ws, size_t ws_size,
                              hipStream_t stream) {
  if (ws_size < (size_t)WS_NEED) return;

  const float* x  = (const float*)d_in[0];
  const float* w1 = (const float*)d_in[1];
  const float* s1 = (const float*)d_in[2];
  const float* w2 = (const float*)d_in[3];
  const float* s2 = (const float*)d_in[4];

  char* ws = (char*)d_ws;
  u32*  wsu = (u32*)ws;
  float* logits = (float*)(ws + WS_LOG);
  _Float16* xh  = (_Float16*)(ws + WS_XH);
  _Float16* w1h = (_Float16*)(ws + WS_W1H);
  _Float16* w2h = (_Float16*)(ws + WS_W2H);
  float* out = (float*)d_out;

  (void)hipFuncSetAttribute((const void*)gemm_fused,
                            hipFuncAttributeMaxDynamicSharedMemorySize, 131072);

  k1_prep<<<CVT_X_BLKS + ZERO_BLKS + H1BLK + H2BLK, 256, 0, stream>>>(x, xh, s1, s2, wsu);
  sel_scan_t<0><<<2, 256, 0, stream>>>(wsu);
  sel_hist1<<<H1BLK + H2BLK, 256, 0, stream>>>(s1, s2, wsu);
  sel_scan_t<1><<<2, 256, 0, stream>>>(wsu);
  sel_collect<<<H1BLK + H2BLK, 256, 0, stream>>>(s1, s2, wsu);
  sel_final<<<2, 256, 0, stream>>>(wsu);
  cvt_w12<<<3392, 256, 0, stream>>>(w1, s1, w2, s2, wsu + WS_META / 4, w1h, w2h);

  gemm_fused<<<2048, 512, 131072, stream>>>(xh, w1h, w2h, logits);
  final_ls<<<BATCH / 256, 256, 0, stream>>>(logits, out);
}

// Round 7
// 556.771 us; speedup vs baseline: 1.2905x; 1.2905x over previous
//
#include <hip/hip_runtime.h>
#include <hip/hip_fp16.h>

typedef _Float16 half8 __attribute__((ext_vector_type(8)));
typedef float f32x4 __attribute__((ext_vector_type(4)));
typedef unsigned long long u64;
typedef unsigned u32;

#define IN_DIM 784
#define KPAD   832            // 13 * 64
#define NKT    13
#define HIDDEN 8192
#define BATCH  16384
#define OUTD   10
#define N1 (HIDDEN * IN_DIM)  // 6422528
#define J1 (N1 / 2)
#define N2 (OUTD * HIDDEN)    // 81920
#define J2 (N2 / 2)

// ---- workspace layout (bytes) ----
#define WS_META 0         // u32[4]: T1,cut1,T2,cut2
#define WS_SEL1 64        // u32[2]: {jrem, prefix}
#define WS_SEL2 96
#define WS_CNT  128       // u32[2]: candidate counts
#define WS_H01  4096      // 2048 u32 (s1 pass0)
#define WS_H02  12288     // 2048 u32 (s2 pass0)
#define WS_H11  20480     // 1024 u32 (s1 pass1)
#define WS_H12  24576     // 1024 u32 (s2 pass1)
#define CTL_ZERO 28672    // zero range [0, CTL_ZERO)
#define WS_CAND1 32768    // 8192 u64
#define WS_CAND2 98304    // 8192 u64
#define WS_LOG  163840    // [16384][10] f32 atomic accumulator
#define WS_XH   (WS_LOG + BATCH * OUTD * 4)            // [16384][832] f16
#define WS_W1H  (WS_XH + (size_t)BATCH * KPAD * 2)     // [8192][832] f16
#define WS_W2H  (WS_W1H + (size_t)HIDDEN * KPAD * 2)   // [16][8192] f16
#define WS_NEED (WS_W2H + 16 * HIDDEN * 2)             // ~41.9 MB

#define CTL_WORDS (CTL_ZERO / 4)                       // 7168
#define ZERO_TOT (CTL_WORDS + BATCH * OUTD)            // 171008 = 668*256
#define CVT_X_BLKS 6656
#define ZERO_BLKS  668
#define H1BLK 256
#define H2BLK 16

// ---------------- K1: cvt_x + zero ctl/hists/logits ----------------
__global__ void k1_prep(const float* __restrict__ x, _Float16* __restrict__ xh,
                        u32* __restrict__ ws) {
  int bx = blockIdx.x;
  if (bx < CVT_X_BLKS) {
    int c = bx * 256 + threadIdx.x;       // 16384*104 chunks of 8
    int row = c / 104, cc = c % 104;
    half8 v;
#pragma unroll
    for (int j = 0; j < 8; ++j) {
      int col = cc * 8 + j;
      float f = (col < IN_DIM) ? x[(size_t)row * IN_DIM + col] : 0.f;
      v[j] = (_Float16)f;
    }
    *(half8*)(xh + (size_t)row * KPAD + cc * 8) = v;
    return;
  }
  int i = (bx - CVT_X_BLKS) * 256 + threadIdx.x;  // exactly ZERO_TOT threads
  if (i < CTL_WORDS) {
    u32 v = 0u;
    if (i == WS_SEL1 / 4) v = J1;
    else if (i == WS_SEL2 / 4) v = J2;
    ws[i] = v;
  } else {
    ws[WS_LOG / 4 + (i - CTL_WORDS)] = 0u;
  }
}

// ---------------- radix-select: 2 histogram passes (LDS + global atomic merge) --------
// key = |score| bits (31b, monotonic). pass0 bins key>>20 (11b); pass1 bins (key>>10)&3FF.
__global__ void sel_hist(const float* __restrict__ s1, const float* __restrict__ s2,
                         u32* __restrict__ ws, int pass) {
  __shared__ u32 lh[2048];
  const int nbins = pass == 0 ? 2048 : 1024;
  for (int i = threadIdx.x; i < nbins; i += 256) lh[i] = 0u;
  __syncthreads();
  const float* s; int n, bid, nb; u32* hist; const u32* sel;
  if (blockIdx.x < H1BLK) {
    s = s1; n = N1; bid = blockIdx.x; nb = H1BLK;
    hist = ws + (pass == 0 ? WS_H01 : WS_H11) / 4; sel = ws + WS_SEL1 / 4;
  } else {
    s = s2; n = N2; bid = blockIdx.x - H1BLK; nb = H2BLK;
    hist = ws + (pass == 0 ? WS_H02 : WS_H12) / 4; sel = ws + WS_SEL2 / 4;
  }
  u32 prefix = sel[1];
  for (int i = bid * 256 + threadIdx.x; i < n; i += nb * 256) {
    u32 k = __float_as_uint(s[i]) & 0x7FFFFFFFu;
    if (pass == 0) atomicAdd(&lh[k >> 20], 1u);
    else if ((k >> 20) == prefix) atomicAdd(&lh[(k >> 10) & 0x3FFu], 1u);
  }
  __syncthreads();
  for (int i = threadIdx.x; i < nbins; i += 256)
    if (lh[i]) atomicAdd(&hist[i], lh[i]);
}

// ---------------- scan: Hillis-Steele over 256 segment sums + register tail ----------------
template <int PASS>
__global__ void sel_scan_t(u32* __restrict__ ws) {
  __shared__ u32 part[256], incl[256];
  constexpr int nbins = PASS == 0 ? 2048 : 1024;
  constexpr int bits  = PASS == 0 ? 11 : 10;
  constexpr int per   = nbins / 256;
  const u32* hist = ws + ((blockIdx.x == 0) ? (PASS == 0 ? WS_H01 : WS_H11)
                                            : (PASS == 0 ? WS_H02 : WS_H12)) / 4;
  u32* sel = ws + ((blockIdx.x == 0) ? WS_SEL1 : WS_SEL2) / 4;
  u32 loc[per]; u32 ssum = 0;
#pragma unroll
  for (int i = 0; i < per; ++i) { loc[i] = hist[threadIdx.x * per + i]; ssum += loc[i]; }
  part[threadIdx.x] = ssum;
  incl[threadIdx.x] = ssum;
  __syncthreads();
  for (int off = 1; off < 256; off <<= 1) {
    u32 v = (threadIdx.x >= off) ? incl[threadIdx.x - off] : 0u;
    __syncthreads();
    incl[threadIdx.x] += v;
    __syncthreads();
  }
  u32 jrem = sel[0];
  u32 excl = incl[threadIdx.x] - part[threadIdx.x];
  if (jrem >= excl && jrem < excl + part[threadIdx.x]) {   // unique owner
    u32 cum = excl; int b = 0;
    for (;; ++b) { if (cum + loc[b] > jrem) break; cum += loc[b]; }
    sel[0] = jrem - cum;
    sel[1] = (sel[1] << bits) | (u32)(threadIdx.x * per + b);
  }
}

// ---------------- collect candidates matching 21-bit prefix ----------------
__global__ void sel_collect(const float* __restrict__ s1, const float* __restrict__ s2,
                            u32* __restrict__ ws) {
  const float* s; int n, bid, nb; u64* cand; u32* cnt; const u32* sel;
  if (blockIdx.x < H1BLK) {
    s = s1; n = N1; bid = blockIdx.x; nb = H1BLK;
    cand = (u64*)(ws + WS_CAND1 / 4); cnt = ws + WS_CNT / 4; sel = ws + WS_SEL1 / 4;
  } else {
    s = s2; n = N2; bid = blockIdx.x - H1BLK; nb = H2BLK;
    cand = (u64*)(ws + WS_CAND2 / 4); cnt = ws + WS_CNT / 4 + 1; sel = ws + WS_SEL2 / 4;
  }
  u32 prefix21 = sel[1];
  for (int i = bid * 256 + threadIdx.x; i < n; i += nb * 256) {
    u32 k = __float_as_uint(s[i]) & 0x7FFFFFFFu;
    if ((k >> 10) == prefix21) {
      u32 p = atomicAdd(cnt, 1u);
      if (p < 8192u) cand[p] = ((u64)k << 32) | (u32)i;
    }
  }
}

// exact rank-m candidate by (key, idx) -> stable argsort tie semantics (LDS-staged)
__global__ void sel_final(u32* __restrict__ ws) {
  __shared__ u64 lc[4096];
  int t = blockIdx.x;
  const u64* cand = (const u64*)(ws + (t == 0 ? WS_CAND1 : WS_CAND2) / 4);
  u32 n = ws[WS_CNT / 4 + t]; if (n > 8192u) n = 8192u;
  u32 nl = n < 4096u ? n : 4096u;
  for (u32 i = threadIdx.x; i < nl; i += 256) lc[i] = cand[i];
  __syncthreads();
  u32 m = ws[(t == 0 ? WS_SEL1 : WS_SEL2) / 4];
  for (u32 ci = threadIdx.x; ci < n; ci += 256) {
    u64 me = (ci < nl) ? lc[ci] : cand[ci];
    u32 r = 0;
    for (u32 j = 0; j < nl; ++j) r += (lc[j] < me) ? 1u : 0u;
    for (u32 j = nl; j < n; ++j) r += (cand[j] < me) ? 1u : 0u;
    if (r == m) {
      ws[WS_META / 4 + t * 2]     = (u32)(me >> 32);
      ws[WS_META / 4 + t * 2 + 1] = (u32)me;
    }
  }
}

// ---------------- masked weight converts (f32 -> padded f16) ----------------
__global__ void cvt_w12(const float* __restrict__ w1, const float* __restrict__ s1,
                        const float* __restrict__ w2, const float* __restrict__ s2,
                        const u32* __restrict__ meta,
                        _Float16* __restrict__ w1h, _Float16* __restrict__ w2h) {
  if (blockIdx.x < 3328) {
    int c = blockIdx.x * 256 + threadIdx.x;     // 8192*104
    int row = c / 104, cc = c % 104;
    u32 T = meta[0], cut = meta[1];
    half8 v;
#pragma unroll
    for (int j = 0; j < 8; ++j) {
      int col = cc * 8 + j;
      float f = 0.f;
      if (col < IN_DIM) {
        u32 flat = (u32)(row * IN_DIM + col);
        u32 k = __float_as_uint(s1[flat]) & 0x7FFFFFFFu;
        bool keep = (k > T) || (k == T && flat >= cut);
        f = keep ? w1[flat] : 0.f;
      }
      v[j] = (_Float16)f;
    }
    *(half8*)(w1h + (size_t)row * KPAD + cc * 8) = v;
  } else {
    int c = (blockIdx.x - 3328) * 256 + threadIdx.x;   // 16*1024
    int o = c >> 10, cc = c & 1023;
    u32 T = meta[2], cut = meta[3];
    half8 v;
#pragma unroll
    for (int j = 0; j < 8; ++j) {
      float f = 0.f;
      if (o < OUTD) {
        u32 flat = (u32)(o * HIDDEN + cc * 8 + j);
        u32 k = __float_as_uint(s2[flat]) & 0x7FFFFFFFu;
        bool keep = (k > T) || (k == T && flat >= cut);
        f = keep ? w2[flat] : 0.f;
      }
      v[j] = (_Float16)f;
    }
    *(half8*)(w2h + (size_t)o * HIDDEN + cc * 8) = v;
  }
}

// ---------------- fused GEMM1 + relu + GEMM2 epilogue ----------------
// 256x256 tile, BK=64, dbuf, ONE sync/tile with full-tile prefetch lead (R3 skeleton),
// but 1024 threads = 16 waves (4x4) -> 4 waves/SIMD for latency hiding between barriers.
__device__ __forceinline__ void gload16(const _Float16* g, _Float16* l) {
  __builtin_amdgcn_global_load_lds((const __attribute__((address_space(1))) void*)g,
                                   (__attribute__((address_space(3))) void*)l, 16, 0, 0);
}

__global__ __launch_bounds__(1024, 4) void gemm_fused(
    const _Float16* __restrict__ xh, const _Float16* __restrict__ w1h,
    const _Float16* __restrict__ w2h, float* __restrict__ logits) {
  extern __shared__ __align__(16) char smem[];   // 131072: 2 x (32K A | 32K B)

  const int tid  = threadIdx.x;
  const int lane = tid & 63;
  const int wid  = tid >> 6;          // 16 waves: 4M x 4N
  const int wm   = wid >> 2, wn = wid & 3;

  // XCD-bijective swizzle (2048 % 8 == 0) + pm-group-of-8 for L2
  int v   = (blockIdx.x & 7) * 256 + (blockIdx.x >> 3);
  int g   = v >> 8, r = v & 255;
  int pm  = g * 8 + (r & 7);          // 0..63
  int pn  = r >> 3;                   // 0..31

  const _Float16* Ab = xh  + (size_t)pm * 256 * KPAD;
  const _Float16* Bb = w1h + (size_t)pn * 256 * KPAD;

  f32x4 acc[4][4] = {};               // wave's 64x64 output

  auto stage = [&](int kt, int b) {   // 64KB tile, 4 gloads/thread
    _Float16* dA = (_Float16*)(smem + b * 65536);
    _Float16* dB = dA + 16384;
#pragma unroll
    for (int i = 0; i < 2; ++i) {
      int slot = i * 1024 + tid;                // 0..2047
      int row  = slot >> 3, ch = slot & 7;
      int cl   = ch ^ (row & 7);                // pre-swizzled source, linear LDS dest
      gload16(Ab + (size_t)row * KPAD + kt * 64 + cl * 8, dA + slot * 8);
      gload16(Bb + (size_t)row * KPAD + kt * 64 + cl * 8, dB + slot * 8);
    }
  };

  stage(0, 0);
  for (int t = 0; t < NKT; ++t) {
    __syncthreads();                  // drains stage(t) (issued a full tile ago)
    if (t + 1 < NKT) stage(t + 1, (t + 1) & 1);
    const _Float16* sA = (const _Float16*)(smem + (t & 1) * 65536);
    const _Float16* sB = sA + 16384;
#pragma unroll
    for (int ks = 0; ks < 2; ++ks) {
      half8 af[4], bf[4];
#pragma unroll
      for (int mi = 0; mi < 4; ++mi) {
        int row = wm * 64 + mi * 16 + (lane & 15);
        int ch  = (ks * 4 + (lane >> 4)) ^ (row & 7);
        af[mi] = *(const half8*)(sA + row * 64 + ch * 8);
      }
#pragma unroll
      for (int ni = 0; ni < 4; ++ni) {
        int row = wn * 64 + ni * 16 + (lane & 15);
        int ch  = (ks * 4 + (lane >> 4)) ^ (row & 7);
        bf[ni] = *(const half8*)(sB + row * 64 + ch * 8);
      }
#pragma unroll
      for (int mi = 0; mi < 4; ++mi)
#pragma unroll
        for (int ni = 0; ni < 4; ++ni)
          acc[mi][ni] = __builtin_amdgcn_mfma_f32_16x16x32_f16(af[mi], bf[ni], acc[mi][ni], 0, 0, 0);
    }
  }

  // ---- epilogue: logits += relu(h) @ w2m^T over this block's 256 n-cols ----
  __syncthreads();                               // all K-loop LDS ops done; reuse LDS
  _Float16* hb = (_Float16*)smem + wid * 2560;   // per-wave [64][40] f16 (80 KB total)
  float* plog  = (float*)(smem + 81920);         // [256][16] f32 (16 KB)

  for (int i = tid; i < 256 * 16; i += 1024) plog[i] = 0.f;

  int o = lane & 15;
  f32x4 lacc[4] = {};
#pragma unroll
  for (int rr = 0; rr < 2; ++rr) {               // two k=32 rounds over wave's 64 cols
#pragma unroll
    for (int mi = 0; mi < 4; ++mi) {
      int r0 = mi * 16 + (lane >> 4) * 4;
#pragma unroll
      for (int nl = 0; nl < 2; ++nl) {
        int ni = 2 * rr + nl;
        int cl = nl * 16 + (lane & 15);
#pragma unroll
        for (int j = 0; j < 4; ++j) {
          float q = acc[mi][ni][j];
          hb[(r0 + j) * 40 + cl] = (_Float16)(q > 0.f ? q : 0.f);
        }
      }
    }
    half8 wbr = *(const half8*)(w2h + (size_t)o * HIDDEN + pn * 256 + wn * 64 + rr * 32 + (lane >> 4) * 8);
#pragma unroll
    for (int mi = 0; mi < 4; ++mi) {
      half8 a = *(const half8*)(hb + (mi * 16 + (lane & 15)) * 40 + (lane >> 4) * 8);
      lacc[mi] = __builtin_amdgcn_mfma_f32_16x16x32_f16(a, wbr, lacc[mi], 0, 0, 0);
    }
  }
  __syncthreads();                               // plog zero visible
  if (o < OUTD) {
#pragma unroll
    for (int mi = 0; mi < 4; ++mi)
#pragma unroll
      for (int j = 0; j < 4; ++j) {
        int row = wm * 64 + mi * 16 + (lane >> 4) * 4 + j;
        atomicAdd(&plog[row * 16 + o], lacc[mi][j]);
      }
  }
  __syncthreads();
  for (int i = tid; i < 256 * OUTD; i += 1024) {
    int row = i / OUTD, oo = i % OUTD;
    atomicAdd(&logits[((size_t)pm * 256 + row) * OUTD + oo], plog[row * 16 + oo]);
  }
}

// ---------------- log_softmax ----------------
__global__ void final_ls(const float* __restrict__ logits, float* __restrict__ out) {
  int row = blockIdx.x * 256 + threadIdx.x;     // 16384
  float l[OUTD];
#pragma unroll
  for (int oo = 0; oo < OUTD; ++oo) l[oo] = logits[(size_t)row * OUTD + oo];
  float mx = l[0];
#pragma unroll
  for (int oo = 1; oo < OUTD; ++oo) mx = fmaxf(mx, l[oo]);
  float s = 0.f;
#pragma unroll
  for (int oo = 0; oo < OUTD; ++oo) s += expf(l[oo] - mx);
  float lse = mx + logf(s);
#pragma unroll
  for (int oo = 0; oo < OUTD; ++oo) out[(size_t)row * OUTD + oo] = l[oo] - lse;
}

// ---------------- launch ----------------
extern "C" void kernel_launch(void* const* d_in, const int* in_sizes, int n_in,
                              void* d_out, int out_size, void* d_ws, size_t ws_size,
                              hipStream_t stream) {
  if (ws_size < (size_t)WS_NEED) return;

  const float* x  = (const float*)d_in[0];
  const float* w1 = (const float*)d_in[1];
  const float* s1 = (const float*)d_in[2];
  const float* w2 = (const float*)d_in[3];
  const float* s2 = (const float*)d_in[4];

  char* ws = (char*)d_ws;
  u32*  wsu = (u32*)ws;
  float* logits = (float*)(ws + WS_LOG);
  _Float16* xh  = (_Float16*)(ws + WS_XH);
  _Float16* w1h = (_Float16*)(ws + WS_W1H);
  _Float16* w2h = (_Float16*)(ws + WS_W2H);
  float* out = (float*)d_out;

  (void)hipFuncSetAttribute((const void*)gemm_fused,
                            hipFuncAttributeMaxDynamicSharedMemorySize, 131072);

  k1_prep<<<CVT_X_BLKS + ZERO_BLKS, 256, 0, stream>>>(x, xh, wsu);

  sel_hist<<<H1BLK + H2BLK, 256, 0, stream>>>(s1, s2, wsu, 0);
  sel_scan_t<0><<<2, 256, 0, stream>>>(wsu);
  sel_hist<<<H1BLK + H2BLK, 256, 0, stream>>>(s1, s2, wsu, 1);
  sel_scan_t<1><<<2, 256, 0, stream>>>(wsu);
  sel_collect<<<H1BLK + H2BLK, 256, 0, stream>>>(s1, s2, wsu);
  sel_final<<<2, 256, 0, stream>>>(wsu);
  cvt_w12<<<3392, 256, 0, stream>>>(w1, s1, w2, s2, wsu + WS_META / 4, w1h, w2h);

  gemm_fused<<<2048, 1024, 131072, stream>>>(xh, w1h, w2h, logits);
  final_ls<<<BATCH / 256, 256, 0, stream>>>(logits, out);
}